// Round 2
// baseline (664.725 us; speedup 1.0000x reference)
//
#include <hip/hip_runtime.h>
#include <math.h>

constexpr int N_NODES  = 100000;
constexpr int N_EDGES  = 3200000;
constexpr int N_GRAPHS = 512;
constexpr int FEAT = 128;
constexpr int H1 = 32;
constexpr int H2 = 16;
constexpr int NCLS = 10;
constexpr int NBLK = (N_NODES + 255) / 256;   // 391 scan blocks

// ---- init: zero degree counts, pooled sums/counts --------------------------
__global__ void k_init(int* __restrict__ cnt, float* __restrict__ psum,
                       float* __restrict__ pcnt) {
    int i = blockIdx.x * 256 + threadIdx.x;
    if (i < N_NODES) cnt[i] = 0;
    if (i < N_GRAPHS * H2) psum[i] = 0.0f;
    if (i < N_GRAPHS) pcnt[i] = 0.0f;
}

// ---- in-degree count over real edges (int atomics, native) -----------------
__global__ void k_count(const int* __restrict__ dst, int* __restrict__ cnt) {
    int e = blockIdx.x * 256 + threadIdx.x;
    if (e < N_EDGES) atomicAdd(&cnt[dst[e]], 1);
}

// ---- scan stage 1: per-256-block exclusive scan ----------------------------
__global__ void k_scan1(const int* __restrict__ cnt, int* __restrict__ cur,
                        int* __restrict__ partial) {
    __shared__ int s[256];
    int tid = threadIdx.x;
    int i = blockIdx.x * 256 + tid;
    int v = (i < N_NODES) ? cnt[i] : 0;
    s[tid] = v;
    __syncthreads();
    for (int d = 1; d < 256; d <<= 1) {
        int t = (tid >= d) ? s[tid - d] : 0;
        __syncthreads();
        s[tid] += t;
        __syncthreads();
    }
    if (i < N_NODES) cur[i] = s[tid] - v;          // block-local exclusive
    if (tid == 255) partial[blockIdx.x] = s[255];  // block total
}

// ---- scan stage 2: single-block exclusive scan of 391 partials -------------
__global__ void k_scan2(int* __restrict__ partial) {
    __shared__ int s[512];
    int tid = threadIdx.x;
    int v = (tid < NBLK) ? partial[tid] : 0;
    s[tid] = v;
    __syncthreads();
    for (int d = 1; d < 512; d <<= 1) {
        int t = (tid >= d) ? s[tid - d] : 0;
        __syncthreads();
        s[tid] += t;
        __syncthreads();
    }
    if (tid < NBLK) partial[tid] = s[tid] - v;
}

// ---- scan stage 3: globalize offsets (cur = CSR start), dinv ---------------
__global__ void k_scan3(const int* __restrict__ cnt, int* __restrict__ cur,
                        const int* __restrict__ partial, float* __restrict__ dinv) {
    int i = blockIdx.x * 256 + threadIdx.x;
    if (i >= N_NODES) return;
    cur[i] += partial[i >> 8];
    dinv[i] = rsqrtf((float)cnt[i] + 1.0f);   // +1 self loop
}

// ---- edge placement: cur[d] walks start->end; esrc grouped by dst ----------
__global__ void k_place(const int* __restrict__ src, const int* __restrict__ dst,
                        int* __restrict__ cur, int* __restrict__ esrc) {
    int e = blockIdx.x * 256 + threadIdx.x;
    if (e >= N_EDGES) return;
    int pos = atomicAdd(&cur[dst[e]], 1);
    esrc[pos] = src[e];
}
// after k_place: cur[i] == segment END; start = cur[i] - cnt[i]

// ---- layer1 GEMM: h1s = (X @ W1) * dinv[i]  (src-side norm pre-applied) ----
__global__ void k_gemm1(const float* __restrict__ X, const float* __restrict__ W1,
                        const float* __restrict__ dinv, float* __restrict__ h1s) {
    int i = blockIdx.x * 256 + threadIdx.x;
    if (i >= N_NODES) return;
    float acc[H1];
#pragma unroll
    for (int j = 0; j < H1; ++j) acc[j] = 0.0f;
    const float4* xr = (const float4*)(X + (size_t)i * FEAT);
    for (int kc = 0; kc < FEAT / 4; ++kc) {
        float4 xv = xr[kc];
        const float* w = W1 + (kc * 4) * H1;   // wave-uniform -> scalar loads
#pragma unroll
        for (int j = 0; j < H1; ++j)
            acc[j] += xv.x * w[j] + xv.y * w[H1 + j]
                    + xv.z * w[2 * H1 + j] + xv.w * w[3 * H1 + j];
    }
    float di = dinv[i];
    float4* hp = (float4*)(h1s + (size_t)i * H1);
#pragma unroll
    for (int q = 0; q < H1 / 4; ++q)
        hp[q] = make_float4(acc[q*4] * di, acc[q*4+1] * di,
                            acc[q*4+2] * di, acc[q*4+3] * di);
}

// ---- layer1 gather: agg1[i] = h1s[i] + sum over incoming edges -------------
// 8 threads per node, each owns a float4 slice of the 32-wide row.
__global__ void k_gather1(const int* __restrict__ cur, const int* __restrict__ cnt,
                          const int* __restrict__ esrc, const float* __restrict__ h1s,
                          float* __restrict__ agg1) {
    int t = blockIdx.x * 256 + threadIdx.x;
    int node = t >> 3;
    if (node >= N_NODES) return;
    int part = t & 7;
    int end = cur[node];
    int beg = end - cnt[node];
    const float4* base = (const float4*)h1s;
    float4 a = base[(size_t)node * (H1/4) + part];          // self loop
    for (int k = beg; k < end; ++k) {
        int s = esrc[k];                                     // broadcast across 8 lanes
        float4 v = base[(size_t)s * (H1/4) + part];          // 128B/row coalesced
        a.x += v.x; a.y += v.y; a.z += v.z; a.w += v.w;
    }
    ((float4*)agg1)[(size_t)node * (H1/4) + part] = a;
}

// ---- layer2 GEMM fused with layer1 bias+relu; h2s = (x @ W2) * dinv --------
__global__ void k_gemm2(const float* __restrict__ agg1, const float* __restrict__ b1,
                        const float* __restrict__ W2, const float* __restrict__ dinv,
                        float* __restrict__ h2s) {
    int i = blockIdx.x * 256 + threadIdx.x;
    if (i >= N_NODES) return;
    float di = dinv[i];
    float x[H1];
    const float4* ar = (const float4*)(agg1 + (size_t)i * H1);
#pragma unroll
    for (int q = 0; q < H1 / 4; ++q) {
        float4 v = ar[q];
        x[q*4+0] = fmaxf(v.x * di + b1[q*4+0], 0.0f);   // dst-side norm applied here
        x[q*4+1] = fmaxf(v.y * di + b1[q*4+1], 0.0f);
        x[q*4+2] = fmaxf(v.z * di + b1[q*4+2], 0.0f);
        x[q*4+3] = fmaxf(v.w * di + b1[q*4+3], 0.0f);
    }
    float acc[H2];
#pragma unroll
    for (int j = 0; j < H2; ++j) acc[j] = 0.0f;
#pragma unroll
    for (int k = 0; k < H1; ++k)
#pragma unroll
        for (int j = 0; j < H2; ++j) acc[j] += x[k] * W2[k * H2 + j];
    float4* hp = (float4*)(h2s + (size_t)i * H2);
#pragma unroll
    for (int q = 0; q < H2 / 4; ++q)
        hp[q] = make_float4(acc[q*4] * di, acc[q*4+1] * di,
                            acc[q*4+2] * di, acc[q*4+3] * di);
}

// ---- layer2 gather: 4 threads per node ------------------------------------
__global__ void k_gather2(const int* __restrict__ cur, const int* __restrict__ cnt,
                          const int* __restrict__ esrc, const float* __restrict__ h2s,
                          float* __restrict__ agg2) {
    int t = blockIdx.x * 256 + threadIdx.x;
    int node = t >> 2;
    if (node >= N_NODES) return;
    int part = t & 3;
    int end = cur[node];
    int beg = end - cnt[node];
    const float4* base = (const float4*)h2s;
    float4 a = base[(size_t)node * (H2/4) + part];
    for (int k = beg; k < end; ++k) {
        int s = esrc[k];
        float4 v = base[(size_t)s * (H2/4) + part];
        a.x += v.x; a.y += v.y; a.z += v.z; a.w += v.w;
    }
    ((float4*)agg2)[(size_t)node * (H2/4) + part] = a;
}

// ---- pool: x2 = relu(agg2*dinv + b2); run-compressed atomics (batch sorted)
__global__ void k_pool(const float* __restrict__ agg2, const float* __restrict__ b2,
                       const float* __restrict__ dinv, const int* __restrict__ batch,
                       float* __restrict__ psum, float* __restrict__ pcnt) {
    constexpr int NCHUNK = (N_NODES + 7) / 8;   // 12500
    int t = blockIdx.x * 256 + threadIdx.x;
    if (t >= NCHUNK * H2) return;
    int c = t >> 4;           // chunk of 8 consecutive nodes
    int j = t & 15;           // feature
    int i0 = c * 8;
    int i1 = i0 + 8; if (i1 > N_NODES) i1 = N_NODES;
    float bj = b2[j];
    int gcur = batch[i0];
    float s = 0.0f, n = 0.0f;
    for (int i = i0; i < i1; ++i) {
        int g = batch[i];
        if (g != gcur) {
            unsafeAtomicAdd(&psum[gcur * H2 + j], s);
            if (j == 0) unsafeAtomicAdd(&pcnt[gcur], n);
            s = 0.0f; n = 0.0f; gcur = g;
        }
        float v = fmaxf(agg2[(size_t)i * H2 + j] * dinv[i] + bj, 0.0f);
        s += v; n += 1.0f;
    }
    unsafeAtomicAdd(&psum[gcur * H2 + j], s);
    if (j == 0) unsafeAtomicAdd(&pcnt[gcur], n);
}

// ---- head: mean, fc, softmax ----------------------------------------------
__global__ void k_head(const float* __restrict__ psum, const float* __restrict__ pcnt,
                       const float* __restrict__ fcw, const float* __restrict__ fcb,
                       float* __restrict__ out) {
    int g = blockIdx.x * 256 + threadIdx.x;
    if (g >= N_GRAPHS) return;
    float inv = 1.0f / fmaxf(pcnt[g], 1.0f);
    float p[H2];
#pragma unroll
    for (int j = 0; j < H2; ++j) p[j] = psum[g * H2 + j] * inv;
    float lg[NCLS];
    float m = -1e30f;
#pragma unroll
    for (int c = 0; c < NCLS; ++c) {
        float s = fcb[c];
#pragma unroll
        for (int j = 0; j < H2; ++j) s += p[j] * fcw[j * NCLS + c];
        lg[c] = s;
        m = fmaxf(m, s);
    }
    float sum = 0.0f;
#pragma unroll
    for (int c = 0; c < NCLS; ++c) { lg[c] = expf(lg[c] - m); sum += lg[c]; }
    float is = 1.0f / sum;
#pragma unroll
    for (int c = 0; c < NCLS; ++c) out[g * NCLS + c] = lg[c] * is;
}

extern "C" void kernel_launch(void* const* d_in, const int* in_sizes, int n_in,
                              void* d_out, int out_size, void* d_ws, size_t ws_size,
                              hipStream_t stream) {
    const float* X   = (const float*)d_in[0];
    const int*   ei  = (const int*)d_in[1];
    const int*   bat = (const int*)d_in[2];
    const float* W1  = (const float*)d_in[3];
    const float* b1  = (const float*)d_in[4];
    const float* W2  = (const float*)d_in[5];
    const float* b2  = (const float*)d_in[6];
    const float* fcw = (const float*)d_in[7];
    const float* fcb = (const float*)d_in[8];
    float* out = (float*)d_out;

    const int* src = ei;
    const int* dst = ei + N_EDGES;

    // workspace carve-up (all 16B-aligned offsets)
    char* ws = (char*)d_ws;
    int*   cnt     = (int*)ws;    ws += (size_t)N_NODES * 4;        // in-degree
    int*   cur     = (int*)ws;    ws += (size_t)N_NODES * 4;        // CSR offset/cursor
    int*   partial = (int*)ws;    ws += 512 * 4;                    // scan partials
    float* dinv    = (float*)ws;  ws += (size_t)N_NODES * 4;
    int*   esrc    = (int*)ws;    ws += (size_t)N_EDGES * 4;        // CSR src lists
    float* h1s     = (float*)ws;  ws += (size_t)N_NODES * H1 * 4;
    float* agg1    = (float*)ws;  ws += (size_t)N_NODES * H1 * 4;
    float* h2s     = (float*)ws;  ws += (size_t)N_NODES * H2 * 4;
    float* agg2    = (float*)ws;  ws += (size_t)N_NODES * H2 * 4;
    float* psum    = (float*)ws;  ws += (size_t)N_GRAPHS * H2 * 4;
    float* pcnt    = (float*)ws;

    int nbN = (N_NODES + 255) / 256;
    int nbE = (N_EDGES + 255) / 256;

    k_init <<<nbN, 256, 0, stream>>>(cnt, psum, pcnt);
    k_count<<<nbE, 256, 0, stream>>>(dst, cnt);
    k_scan1<<<NBLK, 256, 0, stream>>>(cnt, cur, partial);
    k_scan2<<<1, 512, 0, stream>>>(partial);
    k_scan3<<<nbN, 256, 0, stream>>>(cnt, cur, partial, dinv);
    k_place<<<nbE, 256, 0, stream>>>(src, dst, cur, esrc);
    k_gemm1<<<nbN, 256, 0, stream>>>(X, W1, dinv, h1s);
    k_gather1<<<(N_NODES * 8 + 255) / 256, 256, 0, stream>>>(cur, cnt, esrc, h1s, agg1);
    k_gemm2<<<nbN, 256, 0, stream>>>(agg1, b1, W2, dinv, h2s);
    k_gather2<<<(N_NODES * 4 + 255) / 256, 256, 0, stream>>>(cur, cnt, esrc, h2s, agg2);
    k_pool <<<((N_NODES + 7) / 8 * H2 + 255) / 256, 256, 0, stream>>>(agg2, b2, dinv, bat, psum, pcnt);
    k_head <<<(N_GRAPHS + 255) / 256, 256, 0, stream>>>(psum, pcnt, fcw, fcb, out);
}

// Round 3
// 344.969 us; speedup vs baseline: 1.9269x; 1.9269x over previous
//
#include <hip/hip_runtime.h>
#include <math.h>

constexpr int N_NODES  = 100000;
constexpr int N_EDGES  = 3200000;
constexpr int N_GRAPHS = 512;
constexpr int FEAT = 128;
constexpr int H1 = 32;
constexpr int H2 = 16;
constexpr int NCLS = 10;
constexpr int NBUCKET = (N_NODES + 255) / 256;          // 391 buckets of 256 nodes
constexpr int CHUNK   = 8192;                           // edges per bin block
constexpr int NBINBLK = (N_EDGES + CHUNK - 1) / CHUNK;  // 391
constexpr int SRCMASK = 0x1FFFF;                        // 17 bits (100000 < 131072)

// ---- init: zero bucket histogram + pooled sums/counts ----------------------
__global__ void k_init(int* __restrict__ bh, float* __restrict__ psum,
                       float* __restrict__ pcnt) {
    int i = blockIdx.x * 256 + threadIdx.x;
    if (i < NBUCKET) bh[i] = 0;
    if (i < N_GRAPHS * H2) psum[i] = 0.0f;
    if (i < N_GRAPHS) pcnt[i] = 0.0f;
}

// ---- bucket histogram (LDS-staged, 391 global atomics per block) -----------
__global__ void k_hist(const int* __restrict__ dst, int* __restrict__ bh) {
    __shared__ int h[NBUCKET];
    for (int i = threadIdx.x; i < NBUCKET; i += 256) h[i] = 0;
    __syncthreads();
    int base = blockIdx.x * CHUNK;
    int end = base + CHUNK; if (end > N_EDGES) end = N_EDGES;
    for (int e = base + threadIdx.x; e < end; e += 256)
        atomicAdd(&h[dst[e] >> 8], 1);
    __syncthreads();
    for (int i = threadIdx.x; i < NBUCKET; i += 256)
        if (h[i]) atomicAdd(&bh[i], h[i]);
}

// ---- exclusive scan of 391 bucket counts -> bases + cursors ----------------
__global__ void k_bscan(const int* __restrict__ bh, int* __restrict__ bbase,
                        int* __restrict__ bcur) {
    __shared__ int s[512];
    int tid = threadIdx.x;
    int v = (tid < NBUCKET) ? bh[tid] : 0;
    s[tid] = v;
    __syncthreads();
    for (int d = 1; d < 512; d <<= 1) {
        int t = (tid >= d) ? s[tid - d] : 0;
        __syncthreads();
        s[tid] += t;
        __syncthreads();
    }
    if (tid < NBUCKET) { int b = s[tid] - v; bbase[tid] = b; bcur[tid] = b; }
    if (tid == 0) bbase[NBUCKET] = s[NBUCKET - 1];
}

// ---- radix partition: LDS-reorder 8192 edges, burst-write bucket runs ------
__global__ __launch_bounds__(512)
void k_bin(const int* __restrict__ src, const int* __restrict__ dst,
           int* __restrict__ bcur, int* __restrict__ ebkt) {
    __shared__ int val_s[CHUNK];
    __shared__ int adr_s[CHUNK];
    __shared__ int hist[NBUCKET];
    __shared__ int excl[NBUCKET];
    __shared__ int curb[NBUCKET];
    __shared__ int runb[NBUCKET];
    __shared__ int ss[512];
    int tid = threadIdx.x;
    int base = blockIdx.x * CHUNK;
    int cntblk = N_EDGES - base; if (cntblk > CHUNK) cntblk = CHUNK;
    for (int i = tid; i < NBUCKET; i += 512) hist[i] = 0;
    __syncthreads();
    for (int e = tid; e < cntblk; e += 512)
        atomicAdd(&hist[dst[base + e] >> 8], 1);
    __syncthreads();
    // block-local exclusive scan of hist
    int v = (tid < NBUCKET) ? hist[tid] : 0;
    ss[tid] = v;
    __syncthreads();
    for (int d = 1; d < 512; d <<= 1) {
        int t = (tid >= d) ? ss[tid - d] : 0;
        __syncthreads();
        ss[tid] += t;
        __syncthreads();
    }
    if (tid < NBUCKET) {
        int ex = ss[tid] - v;
        excl[tid] = ex;
        curb[tid] = ex;
        runb[tid] = atomicAdd(&bcur[tid], v);   // reserve this block's run
    }
    __syncthreads();
    // scatter into LDS bucket-sorted order; record final global address
    for (int e = tid; e < cntblk; e += 512) {
        int d = dst[base + e];
        int srcv = src[base + e];
        int b = d >> 8;
        int q = atomicAdd(&curb[b], 1);
        val_s[q] = srcv | ((d & 255) << 17);
        adr_s[q] = runb[b] + (q - excl[b]);
    }
    __syncthreads();
    // coalesced drain: consecutive q -> piecewise-consecutive global addrs
    for (int q = tid; q < cntblk; q += 512)
        ebkt[adr_s[q]] = val_s[q];
}

// ---- per-bucket placement: node hist+scan in LDS, exclusive 32KB region ----
__global__ void k_place3(const int* __restrict__ bbase, const int* __restrict__ ebkt,
                         int* __restrict__ start_g, int* __restrict__ cnt_g,
                         float* __restrict__ dinv, int* __restrict__ esrc) {
    __shared__ int hist[256];
    __shared__ int cur[256];
    __shared__ int ss[256];
    int b = blockIdx.x;
    int tid = threadIdx.x;
    int nbase = b << 8;
    int ebase = bbase[b];
    int eend  = bbase[b + 1];
    hist[tid] = 0;
    __syncthreads();
    for (int e = ebase + tid; e < eend; e += 256)
        atomicAdd(&hist[(ebkt[e] >> 17) & 255], 1);
    __syncthreads();
    int v = hist[tid];
    ss[tid] = v;
    __syncthreads();
    for (int d = 1; d < 256; d <<= 1) {
        int t = (tid >= d) ? ss[tid - d] : 0;
        __syncthreads();
        ss[tid] += t;
        __syncthreads();
    }
    int st = ebase + ss[tid] - v;   // global CSR start for node nbase+tid
    cur[tid] = st;
    int node = nbase + tid;
    if (node < N_NODES) {
        start_g[node] = st;
        cnt_g[node] = v;
        dinv[node] = rsqrtf((float)v + 1.0f);   // +1 self loop
    }
    __syncthreads();
    for (int e = ebase + tid; e < eend; e += 256) {
        int p = ebkt[e];
        int pos = atomicAdd(&cur[(p >> 17) & 255], 1);   // LDS cursor
        esrc[pos] = p & SRCMASK;                          // L2-local write
    }
}

// ---- layer1 GEMM: h1s = (X @ W1) * dinv[i] ---------------------------------
__global__ void k_gemm1(const float* __restrict__ X, const float* __restrict__ W1,
                        const float* __restrict__ dinv, float* __restrict__ h1s) {
    int i = blockIdx.x * 256 + threadIdx.x;
    if (i >= N_NODES) return;
    float acc[H1];
#pragma unroll
    for (int j = 0; j < H1; ++j) acc[j] = 0.0f;
    const float4* xr = (const float4*)(X + (size_t)i * FEAT);
    for (int kc = 0; kc < FEAT / 4; ++kc) {
        float4 xv = xr[kc];
        const float* w = W1 + (kc * 4) * H1;   // wave-uniform -> scalar loads
#pragma unroll
        for (int j = 0; j < H1; ++j)
            acc[j] += xv.x * w[j] + xv.y * w[H1 + j]
                    + xv.z * w[2 * H1 + j] + xv.w * w[3 * H1 + j];
    }
    float di = dinv[i];
    float4* hp = (float4*)(h1s + (size_t)i * H1);
#pragma unroll
    for (int q = 0; q < H1 / 4; ++q)
        hp[q] = make_float4(acc[q*4] * di, acc[q*4+1] * di,
                            acc[q*4+2] * di, acc[q*4+3] * di);
}

// ---- layer1 gather: 8 threads/node, float4 slice each ----------------------
__global__ void k_gather1(const int* __restrict__ start_g, const int* __restrict__ cnt_g,
                          const int* __restrict__ esrc, const float* __restrict__ h1s,
                          float* __restrict__ agg1) {
    int t = blockIdx.x * 256 + threadIdx.x;
    int node = t >> 3;
    if (node >= N_NODES) return;
    int part = t & 7;
    int beg = start_g[node];
    int end = beg + cnt_g[node];
    const float4* base = (const float4*)h1s;
    float4 a = base[(size_t)node * (H1/4) + part];          // self loop
    for (int k = beg; k < end; ++k) {
        int s = esrc[k];
        float4 v = base[(size_t)s * (H1/4) + part];
        a.x += v.x; a.y += v.y; a.z += v.z; a.w += v.w;
    }
    ((float4*)agg1)[(size_t)node * (H1/4) + part] = a;
}

// ---- layer2 GEMM fused with layer1 bias+relu -------------------------------
__global__ void k_gemm2(const float* __restrict__ agg1, const float* __restrict__ b1,
                        const float* __restrict__ W2, const float* __restrict__ dinv,
                        float* __restrict__ h2s) {
    int i = blockIdx.x * 256 + threadIdx.x;
    if (i >= N_NODES) return;
    float di = dinv[i];
    float x[H1];
    const float4* ar = (const float4*)(agg1 + (size_t)i * H1);
#pragma unroll
    for (int q = 0; q < H1 / 4; ++q) {
        float4 v = ar[q];
        x[q*4+0] = fmaxf(v.x * di + b1[q*4+0], 0.0f);
        x[q*4+1] = fmaxf(v.y * di + b1[q*4+1], 0.0f);
        x[q*4+2] = fmaxf(v.z * di + b1[q*4+2], 0.0f);
        x[q*4+3] = fmaxf(v.w * di + b1[q*4+3], 0.0f);
    }
    float acc[H2];
#pragma unroll
    for (int j = 0; j < H2; ++j) acc[j] = 0.0f;
#pragma unroll
    for (int k = 0; k < H1; ++k)
#pragma unroll
        for (int j = 0; j < H2; ++j) acc[j] += x[k] * W2[k * H2 + j];
    float4* hp = (float4*)(h2s + (size_t)i * H2);
#pragma unroll
    for (int q = 0; q < H2 / 4; ++q)
        hp[q] = make_float4(acc[q*4] * di, acc[q*4+1] * di,
                            acc[q*4+2] * di, acc[q*4+3] * di);
}

// ---- layer2 gather: 4 threads/node -----------------------------------------
__global__ void k_gather2(const int* __restrict__ start_g, const int* __restrict__ cnt_g,
                          const int* __restrict__ esrc, const float* __restrict__ h2s,
                          float* __restrict__ agg2) {
    int t = blockIdx.x * 256 + threadIdx.x;
    int node = t >> 2;
    if (node >= N_NODES) return;
    int part = t & 3;
    int beg = start_g[node];
    int end = beg + cnt_g[node];
    const float4* base = (const float4*)h2s;
    float4 a = base[(size_t)node * (H2/4) + part];
    for (int k = beg; k < end; ++k) {
        int s = esrc[k];
        float4 v = base[(size_t)s * (H2/4) + part];
        a.x += v.x; a.y += v.y; a.z += v.z; a.w += v.w;
    }
    ((float4*)agg2)[(size_t)node * (H2/4) + part] = a;
}

// ---- pool: x2 = relu(agg2*dinv + b2); run-compressed atomics (batch sorted)
__global__ void k_pool(const float* __restrict__ agg2, const float* __restrict__ b2,
                       const float* __restrict__ dinv, const int* __restrict__ batch,
                       float* __restrict__ psum, float* __restrict__ pcnt) {
    constexpr int NCHUNK = (N_NODES + 7) / 8;
    int t = blockIdx.x * 256 + threadIdx.x;
    if (t >= NCHUNK * H2) return;
    int c = t >> 4;
    int j = t & 15;
    int i0 = c * 8;
    int i1 = i0 + 8; if (i1 > N_NODES) i1 = N_NODES;
    float bj = b2[j];
    int gcur = batch[i0];
    float s = 0.0f, n = 0.0f;
    for (int i = i0; i < i1; ++i) {
        int g = batch[i];
        if (g != gcur) {
            unsafeAtomicAdd(&psum[gcur * H2 + j], s);
            if (j == 0) unsafeAtomicAdd(&pcnt[gcur], n);
            s = 0.0f; n = 0.0f; gcur = g;
        }
        float v = fmaxf(agg2[(size_t)i * H2 + j] * dinv[i] + bj, 0.0f);
        s += v; n += 1.0f;
    }
    unsafeAtomicAdd(&psum[gcur * H2 + j], s);
    if (j == 0) unsafeAtomicAdd(&pcnt[gcur], n);
}

// ---- head: mean, fc, softmax ------------------------------------------------
__global__ void k_head(const float* __restrict__ psum, const float* __restrict__ pcnt,
                       const float* __restrict__ fcw, const float* __restrict__ fcb,
                       float* __restrict__ out) {
    int g = blockIdx.x * 256 + threadIdx.x;
    if (g >= N_GRAPHS) return;
    float inv = 1.0f / fmaxf(pcnt[g], 1.0f);
    float p[H2];
#pragma unroll
    for (int j = 0; j < H2; ++j) p[j] = psum[g * H2 + j] * inv;
    float lg[NCLS];
    float m = -1e30f;
#pragma unroll
    for (int c = 0; c < NCLS; ++c) {
        float s = fcb[c];
#pragma unroll
        for (int j = 0; j < H2; ++j) s += p[j] * fcw[j * NCLS + c];
        lg[c] = s;
        m = fmaxf(m, s);
    }
    float sum = 0.0f;
#pragma unroll
    for (int c = 0; c < NCLS; ++c) { lg[c] = expf(lg[c] - m); sum += lg[c]; }
    float is = 1.0f / sum;
#pragma unroll
    for (int c = 0; c < NCLS; ++c) out[g * NCLS + c] = lg[c] * is;
}

extern "C" void kernel_launch(void* const* d_in, const int* in_sizes, int n_in,
                              void* d_out, int out_size, void* d_ws, size_t ws_size,
                              hipStream_t stream) {
    const float* X   = (const float*)d_in[0];
    const int*   ei  = (const int*)d_in[1];
    const int*   bat = (const int*)d_in[2];
    const float* W1  = (const float*)d_in[3];
    const float* b1  = (const float*)d_in[4];
    const float* W2  = (const float*)d_in[5];
    const float* b2  = (const float*)d_in[6];
    const float* fcw = (const float*)d_in[7];
    const float* fcb = (const float*)d_in[8];
    float* out = (float*)d_out;

    const int* src = ei;
    const int* dst = ei + N_EDGES;

    char* ws = (char*)d_ws;
    int*   bh    = (int*)ws;    ws += 512 * 4;
    int*   bbase = (int*)ws;    ws += 512 * 4;
    int*   bcur  = (int*)ws;    ws += 512 * 4;
    int*   startg= (int*)ws;    ws += (size_t)N_NODES * 4;
    int*   cntg  = (int*)ws;    ws += (size_t)N_NODES * 4;
    float* dinv  = (float*)ws;  ws += (size_t)N_NODES * 4;
    int*   esrc  = (int*)ws;    ws += (size_t)N_EDGES * 4;
    float* h1s   = (float*)ws;  ws += (size_t)N_NODES * H1 * 4;
    float* agg1  = (float*)ws;  ws += (size_t)N_NODES * H1 * 4;
    float* h2s   = (float*)ws;  ws += (size_t)N_NODES * H2 * 4;
    float* agg2  = (float*)ws;  ws += (size_t)N_NODES * H2 * 4;
    float* psum  = (float*)ws;  ws += (size_t)N_GRAPHS * H2 * 4;
    float* pcnt  = (float*)ws;
    // ebkt aliases h1s: ebkt is dead before k_gemm1 writes h1s (same stream)
    int* ebkt = (int*)h1s;

    int nbN = (N_NODES + 255) / 256;

    k_init  <<<32, 256, 0, stream>>>(bh, psum, pcnt);
    k_hist  <<<NBINBLK, 256, 0, stream>>>(dst, bh);
    k_bscan <<<1, 512, 0, stream>>>(bh, bbase, bcur);
    k_bin   <<<NBINBLK, 512, 0, stream>>>(src, dst, bcur, ebkt);
    k_place3<<<NBUCKET, 256, 0, stream>>>(bbase, ebkt, startg, cntg, dinv, esrc);
    k_gemm1 <<<nbN, 256, 0, stream>>>(X, W1, dinv, h1s);
    k_gather1<<<(N_NODES * 8 + 255) / 256, 256, 0, stream>>>(startg, cntg, esrc, h1s, agg1);
    k_gemm2 <<<nbN, 256, 0, stream>>>(agg1, b1, W2, dinv, h2s);
    k_gather2<<<(N_NODES * 4 + 255) / 256, 256, 0, stream>>>(startg, cntg, esrc, h2s, agg2);
    k_pool  <<<((N_NODES + 7) / 8 * H2 + 255) / 256, 256, 0, stream>>>(agg2, b2, dinv, bat, psum, pcnt);
    k_head  <<<(N_GRAPHS + 255) / 256, 256, 0, stream>>>(psum, pcnt, fcw, fcb, out);
}

// Round 4
// 319.083 us; speedup vs baseline: 2.0832x; 1.0811x over previous
//
#include <hip/hip_runtime.h>
#include <math.h>

constexpr int N_NODES  = 100000;
constexpr int N_EDGES  = 3200000;
constexpr int N_GRAPHS = 512;
constexpr int FEAT = 128;
constexpr int H1 = 32;
constexpr int H2 = 16;
constexpr int NCLS = 10;
constexpr int NBUCKET = (N_NODES + 255) / 256;          // 391 buckets of 256 nodes
constexpr int CHUNK   = 8192;                           // edges per bin block
constexpr int NBINBLK = (N_EDGES + CHUNK - 1) / CHUNK;  // 391
constexpr int CAP     = 10240;   // bucket capacity; mean 8184, sigma 90 -> 23 sigma slack
constexpr int SRCMASK = 0x1FFFF;                        // 17 bits (100000 < 131072)

// ---- init: bucket cursors at fixed bases; zero pooled sums/counts ----------
__global__ void k_init(int* __restrict__ bcur, float* __restrict__ psum,
                       float* __restrict__ pcnt) {
    int i = blockIdx.x * 256 + threadIdx.x;
    if (i < NBUCKET) bcur[i] = i * CAP;
    if (i < N_GRAPHS * H2) psum[i] = 0.0f;
    if (i < N_GRAPHS) pcnt[i] = 0.0f;
}

// ---- radix partition: LDS-reorder 8192 edges, burst-write bucket runs ------
__global__ __launch_bounds__(512)
void k_bin(const int* __restrict__ src, const int* __restrict__ dst,
           int* __restrict__ bcur, int* __restrict__ ebkt) {
    __shared__ int val_s[CHUNK];
    __shared__ int adr_s[CHUNK];
    __shared__ int hist[NBUCKET];
    __shared__ int excl[NBUCKET];
    __shared__ int curb[NBUCKET];
    __shared__ int runb[NBUCKET];
    __shared__ int ss[512];
    int tid = threadIdx.x;
    int base = blockIdx.x * CHUNK;
    int cntblk = N_EDGES - base; if (cntblk > CHUNK) cntblk = CHUNK;
    for (int i = tid; i < NBUCKET; i += 512) hist[i] = 0;
    __syncthreads();
    for (int e = tid; e < cntblk; e += 512)
        atomicAdd(&hist[dst[base + e] >> 8], 1);
    __syncthreads();
    int v = (tid < NBUCKET) ? hist[tid] : 0;
    ss[tid] = v;
    __syncthreads();
    for (int d = 1; d < 512; d <<= 1) {
        int t = (tid >= d) ? ss[tid - d] : 0;
        __syncthreads();
        ss[tid] += t;
        __syncthreads();
    }
    if (tid < NBUCKET) {
        int ex = ss[tid] - v;
        excl[tid] = ex;
        curb[tid] = ex;
        runb[tid] = atomicAdd(&bcur[tid], v);   // reserve this block's run
    }
    __syncthreads();
    for (int e = tid; e < cntblk; e += 512) {
        int d = dst[base + e];
        int srcv = src[base + e];
        int b = d >> 8;
        int q = atomicAdd(&curb[b], 1);
        val_s[q] = srcv | ((d & 255) << 17);
        adr_s[q] = runb[b] + (q - excl[b]);
    }
    __syncthreads();
    for (int q = tid; q < cntblk; q += 512)
        ebkt[adr_s[q]] = val_s[q];
}

// ---- per-bucket placement: node hist+scan in LDS, exclusive region ---------
__global__ void k_place3(const int* __restrict__ bcur, const int* __restrict__ ebkt,
                         int* __restrict__ start_g, int* __restrict__ cnt_g,
                         float* __restrict__ dinv, int* __restrict__ esrc) {
    __shared__ int hist[256];
    __shared__ int cur[256];
    __shared__ int ss[256];
    int b = blockIdx.x;
    int tid = threadIdx.x;
    int nbase = b << 8;
    int ebase = b * CAP;
    int eend  = bcur[b];          // base + bucket count (after k_bin)
    hist[tid] = 0;
    __syncthreads();
    for (int e = ebase + tid; e < eend; e += 256)
        atomicAdd(&hist[(ebkt[e] >> 17) & 255], 1);
    __syncthreads();
    int v = hist[tid];
    ss[tid] = v;
    __syncthreads();
    for (int d = 1; d < 256; d <<= 1) {
        int t = (tid >= d) ? ss[tid - d] : 0;
        __syncthreads();
        ss[tid] += t;
        __syncthreads();
    }
    int st = ebase + ss[tid] - v;
    cur[tid] = st;
    int node = nbase + tid;
    if (node < N_NODES) {
        start_g[node] = st;
        cnt_g[node] = v;
        dinv[node] = rsqrtf((float)v + 1.0f);   // +1 self loop
    }
    __syncthreads();
    for (int e = ebase + tid; e < eend; e += 256) {
        int p = ebkt[e];
        int pos = atomicAdd(&cur[(p >> 17) & 255], 1);
        esrc[pos] = p & SRCMASK;
    }
}

// ---- layer1 GEMM: h1s = (X @ W1) * dinv[i] ---------------------------------
__global__ void k_gemm1(const float* __restrict__ X, const float* __restrict__ W1,
                        const float* __restrict__ dinv, float* __restrict__ h1s) {
    int i = blockIdx.x * 256 + threadIdx.x;
    if (i >= N_NODES) return;
    float acc[H1];
#pragma unroll
    for (int j = 0; j < H1; ++j) acc[j] = 0.0f;
    const float4* xr = (const float4*)(X + (size_t)i * FEAT);
    for (int kc = 0; kc < FEAT / 4; ++kc) {
        float4 xv = xr[kc];
        const float* w = W1 + (kc * 4) * H1;   // wave-uniform -> scalar loads
#pragma unroll
        for (int j = 0; j < H1; ++j)
            acc[j] += xv.x * w[j] + xv.y * w[H1 + j]
                    + xv.z * w[2 * H1 + j] + xv.w * w[3 * H1 + j];
    }
    float di = dinv[i];
    float4* hp = (float4*)(h1s + (size_t)i * H1);
#pragma unroll
    for (int q = 0; q < H1 / 4; ++q)
        hp[q] = make_float4(acc[q*4] * di, acc[q*4+1] * di,
                            acc[q*4+2] * di, acc[q*4+3] * di);
}

// ---- fused gather1 + bias/relu + gemm2: h2s written directly ---------------
// 8 lanes/node; lane owns feats 4q..4q+3 of the 32-wide row; shuffle-tree
// reduces the 32x16 GEMM partials, splitting feature ownership each step
// (static indices only -> no scratch).
__global__ void k_gA(const int* __restrict__ start_g, const int* __restrict__ cnt_g,
                     const int* __restrict__ esrc, const float* __restrict__ h1s,
                     const float* __restrict__ b1, const float* __restrict__ W2,
                     const float* __restrict__ dinv, float* __restrict__ h2s) {
    int t = blockIdx.x * 256 + threadIdx.x;
    int node = t >> 3;            // grid sized exactly: no guard needed
    int lane = t & 7;
    int beg = start_g[node];
    int end = beg + cnt_g[node];
    const float4* base = (const float4*)h1s;
    float4 a = base[(size_t)node * 8 + lane];   // self loop
    int k = beg;
    for (; k + 2 <= end; k += 2) {
        int s0 = esrc[k];
        int s1 = esrc[k + 1];
        float4 v0 = base[(size_t)s0 * 8 + lane];
        float4 v1 = base[(size_t)s1 * 8 + lane];
        a.x += v0.x + v1.x; a.y += v0.y + v1.y;
        a.z += v0.z + v1.z; a.w += v0.w + v1.w;
    }
    if (k < end) {
        int s0 = esrc[k];
        float4 v0 = base[(size_t)s0 * 8 + lane];
        a.x += v0.x; a.y += v0.y; a.z += v0.z; a.w += v0.w;
    }
    float di = dinv[node];
    // layer-1 epilogue: dst-side norm + bias + relu
    float x0 = fmaxf(a.x * di + b1[4*lane+0], 0.0f);
    float x1 = fmaxf(a.y * di + b1[4*lane+1], 0.0f);
    float x2 = fmaxf(a.z * di + b1[4*lane+2], 0.0f);
    float x3 = fmaxf(a.w * di + b1[4*lane+3], 0.0f);
    // per-lane partial of x @ W2 over my 4 k's
    float acc[H2];
    const float* w0 = W2 + (4*lane+0) * H2;
    const float* w1 = W2 + (4*lane+1) * H2;
    const float* w2 = W2 + (4*lane+2) * H2;
    const float* w3 = W2 + (4*lane+3) * H2;
#pragma unroll
    for (int j = 0; j < H2; ++j)
        acc[j] = x0 * w0[j] + x1 * w1[j] + x2 * w2[j] + x3 * w3[j];
    // step 1: xor 1, split 16 -> 8 (feat bit 3 = lane bit 0)
    float p16[16];
#pragma unroll
    for (int j = 0; j < 16; ++j) p16[j] = __shfl_xor(acc[j], 1);
    float r8[8];
    if (lane & 1) {
#pragma unroll
        for (int j = 0; j < 8; ++j) r8[j] = acc[8+j] + p16[8+j];
    } else {
#pragma unroll
        for (int j = 0; j < 8; ++j) r8[j] = acc[j] + p16[j];
    }
    // step 2: xor 2, split 8 -> 4 (feat bit 2 = lane bit 1)
    float p8[8];
#pragma unroll
    for (int j = 0; j < 8; ++j) p8[j] = __shfl_xor(r8[j], 2);
    float r4[4];
    if (lane & 2) {
#pragma unroll
        for (int j = 0; j < 4; ++j) r4[j] = r8[4+j] + p8[4+j];
    } else {
#pragma unroll
        for (int j = 0; j < 4; ++j) r4[j] = r8[j] + p8[j];
    }
    // step 3: xor 4, split 4 -> 2 (feat bit 1 = lane bit 2)
    float p4[4];
#pragma unroll
    for (int j = 0; j < 4; ++j) p4[j] = __shfl_xor(r4[j], 4);
    float r2[2];
    if (lane & 4) {
        r2[0] = r4[2] + p4[2]; r2[1] = r4[3] + p4[3];
    } else {
        r2[0] = r4[0] + p4[0]; r2[1] = r4[1] + p4[1];
    }
    int fb = ((lane & 1) << 3) | (((lane >> 1) & 1) << 2) | (((lane >> 2) & 1) << 1);
    // layer-2 src-side norm pre-applied
    *(float2*)(h2s + (size_t)node * H2 + fb) = make_float2(r2[0] * di, r2[1] * di);
}

// ---- fused gather2 + bias/relu + mean-pool accumulation --------------------
// 4 lanes/node; wave = 16 consecutive nodes; sorted batch -> fast-path
// butterfly reduce then 16 atomics/wave.
__global__ void k_gB(const int* __restrict__ start_g, const int* __restrict__ cnt_g,
                     const int* __restrict__ esrc, const float* __restrict__ h2s,
                     const float* __restrict__ b2, const float* __restrict__ dinv,
                     const int* __restrict__ batch,
                     float* __restrict__ psum, float* __restrict__ pcnt) {
    int t = blockIdx.x * 256 + threadIdx.x;
    int node = t >> 2;
    int q = t & 3;
    bool valid = node < N_NODES;
    int nd = valid ? node : (N_NODES - 1);
    int beg = start_g[nd];
    int end = beg + cnt_g[nd];
    const float4* base = (const float4*)h2s;
    float4 a = base[(size_t)nd * 4 + q];   // self loop
    int k = beg;
    for (; k + 2 <= end; k += 2) {
        int s0 = esrc[k];
        int s1 = esrc[k + 1];
        float4 v0 = base[(size_t)s0 * 4 + q];
        float4 v1 = base[(size_t)s1 * 4 + q];
        a.x += v0.x + v1.x; a.y += v0.y + v1.y;
        a.z += v0.z + v1.z; a.w += v0.w + v1.w;
    }
    if (k < end) {
        int s0 = esrc[k];
        float4 v0 = base[(size_t)s0 * 4 + q];
        a.x += v0.x; a.y += v0.y; a.z += v0.z; a.w += v0.w;
    }
    float di = dinv[nd];
    float4 v;
    v.x = fmaxf(a.x * di + b2[4*q+0], 0.0f);
    v.y = fmaxf(a.y * di + b2[4*q+1], 0.0f);
    v.z = fmaxf(a.z * di + b2[4*q+2], 0.0f);
    v.w = fmaxf(a.w * di + b2[4*q+3], 0.0f);
    if (!valid) { v.x = v.y = v.z = v.w = 0.0f; }
    float c = (valid && q == 0) ? 1.0f : 0.0f;
    int g = batch[nd];
    int lane = threadIdx.x & 63;
    int g0 = __shfl(g, 0);
    bool uni = (__ballot(g == g0) == ~0ull);
    if (uni) {
#pragma unroll
        for (int m = 4; m <= 32; m <<= 1) {
            v.x += __shfl_xor(v.x, m);
            v.y += __shfl_xor(v.y, m);
            v.z += __shfl_xor(v.z, m);
            v.w += __shfl_xor(v.w, m);
            c   += __shfl_xor(c, m);
        }
        if (lane < 4) {   // lane == q for these
            float* ps = psum + g0 * H2 + lane * 4;
            unsafeAtomicAdd(ps + 0, v.x);
            unsafeAtomicAdd(ps + 1, v.y);
            unsafeAtomicAdd(ps + 2, v.z);
            unsafeAtomicAdd(ps + 3, v.w);
        }
        if (lane == 0) unsafeAtomicAdd(&pcnt[g0], c);
    } else if (valid) {
        float* ps = psum + g * H2 + 4 * q;
        unsafeAtomicAdd(ps + 0, v.x);
        unsafeAtomicAdd(ps + 1, v.y);
        unsafeAtomicAdd(ps + 2, v.z);
        unsafeAtomicAdd(ps + 3, v.w);
        if (q == 0) unsafeAtomicAdd(&pcnt[g], 1.0f);
    }
}

// ---- head: mean, fc, softmax ------------------------------------------------
__global__ void k_head(const float* __restrict__ psum, const float* __restrict__ pcnt,
                       const float* __restrict__ fcw, const float* __restrict__ fcb,
                       float* __restrict__ out) {
    int g = blockIdx.x * 256 + threadIdx.x;
    if (g >= N_GRAPHS) return;
    float inv = 1.0f / fmaxf(pcnt[g], 1.0f);
    float p[H2];
#pragma unroll
    for (int j = 0; j < H2; ++j) p[j] = psum[g * H2 + j] * inv;
    float lg[NCLS];
    float m = -1e30f;
#pragma unroll
    for (int c = 0; c < NCLS; ++c) {
        float s = fcb[c];
#pragma unroll
        for (int j = 0; j < H2; ++j) s += p[j] * fcw[j * NCLS + c];
        lg[c] = s;
        m = fmaxf(m, s);
    }
    float sum = 0.0f;
#pragma unroll
    for (int c = 0; c < NCLS; ++c) { lg[c] = expf(lg[c] - m); sum += lg[c]; }
    float is = 1.0f / sum;
#pragma unroll
    for (int c = 0; c < NCLS; ++c) out[g * NCLS + c] = lg[c] * is;
}

extern "C" void kernel_launch(void* const* d_in, const int* in_sizes, int n_in,
                              void* d_out, int out_size, void* d_ws, size_t ws_size,
                              hipStream_t stream) {
    const float* X   = (const float*)d_in[0];
    const int*   ei  = (const int*)d_in[1];
    const int*   bat = (const int*)d_in[2];
    const float* W1  = (const float*)d_in[3];
    const float* b1  = (const float*)d_in[4];
    const float* W2  = (const float*)d_in[5];
    const float* b2  = (const float*)d_in[6];
    const float* fcw = (const float*)d_in[7];
    const float* fcb = (const float*)d_in[8];
    float* out = (float*)d_out;

    const int* src = ei;
    const int* dst = ei + N_EDGES;

    char* ws = (char*)d_ws;
    int*   bcur  = (int*)ws;    ws += 512 * 4;
    int*   startg= (int*)ws;    ws += (size_t)N_NODES * 4;
    int*   cntg  = (int*)ws;    ws += (size_t)N_NODES * 4;
    float* dinv  = (float*)ws;  ws += (size_t)N_NODES * 4;
    int*   esrc  = (int*)ws;    ws += (size_t)NBUCKET * CAP * 4;   // 16 MB, gapped CSR
    float* h1s   = (float*)ws;  ws += (size_t)N_NODES * H1 * 4;    // 12.8 MB
    float* h2s   = (float*)ws;  ws += (size_t)N_NODES * H2 * 4;    // 6.4 MB
    float* psum  = (float*)ws;  ws += (size_t)N_GRAPHS * H2 * 4;
    float* pcnt  = (float*)ws;
    // ebkt (16 MB) aliases h1s+h2s (19.2 MB): dead before k_gemm1/k_gA write them
    int* ebkt = (int*)h1s;

    int nbN = (N_NODES + 255) / 256;

    k_init  <<<32, 256, 0, stream>>>(bcur, psum, pcnt);
    k_bin   <<<NBINBLK, 512, 0, stream>>>(src, dst, bcur, ebkt);
    k_place3<<<NBUCKET, 256, 0, stream>>>(bcur, ebkt, startg, cntg, dinv, esrc);
    k_gemm1 <<<nbN, 256, 0, stream>>>(X, W1, dinv, h1s);
    k_gA    <<<(N_NODES * 8) / 256, 256, 0, stream>>>(startg, cntg, esrc, h1s, b1, W2, dinv, h2s);
    k_gB    <<<(N_NODES * 4 + 255) / 256, 256, 0, stream>>>(startg, cntg, esrc, h2s, b2, dinv, bat, psum, pcnt);
    k_head  <<<(N_GRAPHS + 255) / 256, 256, 0, stream>>>(psum, pcnt, fcw, fcb, out);
}

// Round 5
// 287.285 us; speedup vs baseline: 2.3138x; 1.1107x over previous
//
#include <hip/hip_runtime.h>
#include <math.h>

constexpr int N_NODES  = 100000;
constexpr int N_EDGES  = 3200000;
constexpr int N_GRAPHS = 512;
constexpr int FEAT = 128;
constexpr int H1 = 32;
constexpr int H2 = 16;
constexpr int NCLS = 10;
constexpr int NBUCKET = (N_NODES + 255) / 256;          // 391 buckets of 256 nodes
constexpr int CHUNK   = 8192;                           // edges per bin block
constexpr int NBINBLK = (N_EDGES + CHUNK - 1) / CHUNK;  // 391
constexpr int CAP     = 10240;   // bucket capacity; mean 8184, sigma 90 -> 23 sigma slack
constexpr int SRCMASK = 0x1FFFF;                        // 17 bits (100000 < 131072)

// ---- init: bucket cursors at fixed bases; zero pooled sums/counts ----------
__global__ void k_init(int* __restrict__ bcur, float* __restrict__ psum,
                       float* __restrict__ pcnt) {
    int i = blockIdx.x * 256 + threadIdx.x;
    if (i < NBUCKET) bcur[i] = i * CAP;
    if (i < N_GRAPHS * H2) psum[i] = 0.0f;
    if (i < N_GRAPHS) pcnt[i] = 0.0f;
}

// ---- radix partition: LDS-reorder 8192 edges, burst-write bucket runs ------
__global__ __launch_bounds__(512)
void k_bin(const int* __restrict__ src, const int* __restrict__ dst,
           int* __restrict__ bcur, int* __restrict__ ebkt) {
    __shared__ int val_s[CHUNK];
    __shared__ int adr_s[CHUNK];
    __shared__ int hist[NBUCKET];
    __shared__ int excl[NBUCKET];
    __shared__ int curb[NBUCKET];
    __shared__ int runb[NBUCKET];
    __shared__ int ss[512];
    int tid = threadIdx.x;
    int base = blockIdx.x * CHUNK;
    int cntblk = N_EDGES - base; if (cntblk > CHUNK) cntblk = CHUNK;
    for (int i = tid; i < NBUCKET; i += 512) hist[i] = 0;
    __syncthreads();
    for (int e = tid; e < cntblk; e += 512)
        atomicAdd(&hist[dst[base + e] >> 8], 1);
    __syncthreads();
    int v = (tid < NBUCKET) ? hist[tid] : 0;
    ss[tid] = v;
    __syncthreads();
    for (int d = 1; d < 512; d <<= 1) {
        int t = (tid >= d) ? ss[tid - d] : 0;
        __syncthreads();
        ss[tid] += t;
        __syncthreads();
    }
    if (tid < NBUCKET) {
        int ex = ss[tid] - v;
        excl[tid] = ex;
        curb[tid] = ex;
        runb[tid] = atomicAdd(&bcur[tid], v);   // reserve this block's run
    }
    __syncthreads();
    for (int e = tid; e < cntblk; e += 512) {
        int d = dst[base + e];
        int srcv = src[base + e];
        int b = d >> 8;
        int q = atomicAdd(&curb[b], 1);
        val_s[q] = srcv | ((d & 255) << 17);
        adr_s[q] = runb[b] + (q - excl[b]);
    }
    __syncthreads();
    for (int q = tid; q < cntblk; q += 512)
        ebkt[adr_s[q]] = val_s[q];
}

// ---- per-bucket placement: node hist+scan in LDS, exclusive region ---------
__global__ void k_place3(const int* __restrict__ bcur, const int* __restrict__ ebkt,
                         int* __restrict__ start_g, int* __restrict__ cnt_g,
                         float* __restrict__ dinv, int* __restrict__ esrc) {
    __shared__ int hist[256];
    __shared__ int cur[256];
    __shared__ int ss[256];
    int b = blockIdx.x;
    int tid = threadIdx.x;
    int nbase = b << 8;
    int ebase = b * CAP;
    int eend  = bcur[b];          // base + bucket count (after k_bin)
    hist[tid] = 0;
    __syncthreads();
    for (int e = ebase + tid; e < eend; e += 256)
        atomicAdd(&hist[(ebkt[e] >> 17) & 255], 1);
    __syncthreads();
    int v = hist[tid];
    ss[tid] = v;
    __syncthreads();
    for (int d = 1; d < 256; d <<= 1) {
        int t = (tid >= d) ? ss[tid - d] : 0;
        __syncthreads();
        ss[tid] += t;
        __syncthreads();
    }
    int st = ebase + ss[tid] - v;
    cur[tid] = st;
    int node = nbase + tid;
    if (node < N_NODES) {
        start_g[node] = st;
        cnt_g[node] = v;
        dinv[node] = rsqrtf((float)v + 1.0f);   // +1 self loop
    }
    __syncthreads();
    for (int e = ebase + tid; e < eend; e += 256) {
        int p = ebkt[e];
        int pos = atomicAdd(&cur[(p >> 17) & 255], 1);
        esrc[pos] = p & SRCMASK;
    }
}

// ---- layer1 GEMM: h1s = (X @ W1) * dinv[i] ---------------------------------
__global__ void k_gemm1(const float* __restrict__ X, const float* __restrict__ W1,
                        const float* __restrict__ dinv, float* __restrict__ h1s) {
    int i = blockIdx.x * 256 + threadIdx.x;
    if (i >= N_NODES) return;
    float acc[H1];
#pragma unroll
    for (int j = 0; j < H1; ++j) acc[j] = 0.0f;
    const float4* xr = (const float4*)(X + (size_t)i * FEAT);
    for (int kc = 0; kc < FEAT / 4; ++kc) {
        float4 xv = xr[kc];
        const float* w = W1 + (kc * 4) * H1;   // wave-uniform -> scalar loads
#pragma unroll
        for (int j = 0; j < H1; ++j)
            acc[j] += xv.x * w[j] + xv.y * w[H1 + j]
                    + xv.z * w[2 * H1 + j] + xv.w * w[3 * H1 + j];
    }
    float di = dinv[i];
    float4* hp = (float4*)(h1s + (size_t)i * H1);
#pragma unroll
    for (int q = 0; q < H1 / 4; ++q)
        hp[q] = make_float4(acc[q*4] * di, acc[q*4+1] * di,
                            acc[q*4+2] * di, acc[q*4+3] * di);
}

// ---- fused gather1 + bias/relu + gemm2 -------------------------------------
// 8 lanes/node. Chunk-8 MLP: one coalesced esrc dword/lane, width-8 shfl
// broadcast, 8 row-loads in flight, single wait, 32 adds. Next chunk's esrc
// prefetched before the row waits.
__global__ void k_gA(const int* __restrict__ start_g, const int* __restrict__ cnt_g,
                     const int* __restrict__ esrc, const float* __restrict__ h1s,
                     const float* __restrict__ b1, const float* __restrict__ W2,
                     const float* __restrict__ dinv, float* __restrict__ h2s) {
    int t = blockIdx.x * 256 + threadIdx.x;
    int node = t >> 3;            // grid sized exactly
    int lane = t & 7;
    int beg = start_g[node];
    int cnt = cnt_g[node];
    const float4* base = (const float4*)h1s;
    float4 a = base[(size_t)node * 8 + lane];   // self loop
    int nfull = cnt >> 3;
    int rem = cnt & 7;
    int ev = (nfull > 0) ? esrc[beg + lane]
           : ((lane < rem) ? esrc[beg + lane] : 0);
    for (int c = 0; c < nfull; ++c) {
        int evn = 0;   // prefetch next chunk (or tail) before waiting on rows
        if (c + 1 < nfull) evn = esrc[beg + (c + 1) * 8 + lane];
        else if (lane < rem) evn = esrc[beg + nfull * 8 + lane];
        float4 v0 = base[(size_t)__shfl(ev, 0, 8) * 8 + lane];
        float4 v1 = base[(size_t)__shfl(ev, 1, 8) * 8 + lane];
        float4 v2 = base[(size_t)__shfl(ev, 2, 8) * 8 + lane];
        float4 v3 = base[(size_t)__shfl(ev, 3, 8) * 8 + lane];
        float4 v4 = base[(size_t)__shfl(ev, 4, 8) * 8 + lane];
        float4 v5 = base[(size_t)__shfl(ev, 5, 8) * 8 + lane];
        float4 v6 = base[(size_t)__shfl(ev, 6, 8) * 8 + lane];
        float4 v7 = base[(size_t)__shfl(ev, 7, 8) * 8 + lane];
        a.x += ((v0.x + v1.x) + (v2.x + v3.x)) + ((v4.x + v5.x) + (v6.x + v7.x));
        a.y += ((v0.y + v1.y) + (v2.y + v3.y)) + ((v4.y + v5.y) + (v6.y + v7.y));
        a.z += ((v0.z + v1.z) + (v2.z + v3.z)) + ((v4.z + v5.z) + (v6.z + v7.z));
        a.w += ((v0.w + v1.w) + (v2.w + v3.w)) + ((v4.w + v5.w) + (v6.w + v7.w));
        ev = evn;
    }
    if (rem) {
#pragma unroll
        for (int j = 0; j < 8; ++j) {
            int sj = __shfl(ev, j, 8);
            bool val = (j < rem);
            float4 v = base[(size_t)(val ? sj : node) * 8 + lane];  // node row: L1-hot
            float m = val ? 1.0f : 0.0f;
            a.x += v.x * m; a.y += v.y * m; a.z += v.z * m; a.w += v.w * m;
        }
    }
    float di = dinv[node];
    // layer-1 epilogue: dst-side norm + bias + relu
    float x0 = fmaxf(a.x * di + b1[4*lane+0], 0.0f);
    float x1 = fmaxf(a.y * di + b1[4*lane+1], 0.0f);
    float x2 = fmaxf(a.z * di + b1[4*lane+2], 0.0f);
    float x3 = fmaxf(a.w * di + b1[4*lane+3], 0.0f);
    // per-lane partial of x @ W2 over my 4 k's
    float acc[H2];
    const float* w0 = W2 + (4*lane+0) * H2;
    const float* w1 = W2 + (4*lane+1) * H2;
    const float* w2 = W2 + (4*lane+2) * H2;
    const float* w3 = W2 + (4*lane+3) * H2;
#pragma unroll
    for (int j = 0; j < H2; ++j)
        acc[j] = x0 * w0[j] + x1 * w1[j] + x2 * w2[j] + x3 * w3[j];
    // shuffle-tree reduce, splitting feature ownership each step
    float p16[16];
#pragma unroll
    for (int j = 0; j < 16; ++j) p16[j] = __shfl_xor(acc[j], 1);
    float r8[8];
    if (lane & 1) {
#pragma unroll
        for (int j = 0; j < 8; ++j) r8[j] = acc[8+j] + p16[8+j];
    } else {
#pragma unroll
        for (int j = 0; j < 8; ++j) r8[j] = acc[j] + p16[j];
    }
    float p8[8];
#pragma unroll
    for (int j = 0; j < 8; ++j) p8[j] = __shfl_xor(r8[j], 2);
    float r4[4];
    if (lane & 2) {
#pragma unroll
        for (int j = 0; j < 4; ++j) r4[j] = r8[4+j] + p8[4+j];
    } else {
#pragma unroll
        for (int j = 0; j < 4; ++j) r4[j] = r8[j] + p8[j];
    }
    float p4[4];
#pragma unroll
    for (int j = 0; j < 4; ++j) p4[j] = __shfl_xor(r4[j], 4);
    float r2[2];
    if (lane & 4) {
        r2[0] = r4[2] + p4[2]; r2[1] = r4[3] + p4[3];
    } else {
        r2[0] = r4[0] + p4[0]; r2[1] = r4[1] + p4[1];
    }
    int fb = ((lane & 1) << 3) | (((lane >> 1) & 1) << 2) | (((lane >> 2) & 1) << 1);
    *(float2*)(h2s + (size_t)node * H2 + fb) = make_float2(r2[0] * di, r2[1] * di);
}

// ---- fused gather2 + bias/relu + mean-pool ---------------------------------
// 8 lanes/node, float2 slice each; chunk-8 MLP as in k_gA; sorted batch ->
// wave (8 nodes) usually one graph: butterfly reduce, 16+1 atomics/wave.
__global__ void k_gB(const int* __restrict__ start_g, const int* __restrict__ cnt_g,
                     const int* __restrict__ esrc, const float* __restrict__ h2s,
                     const float* __restrict__ b2, const float* __restrict__ dinv,
                     const int* __restrict__ batch,
                     float* __restrict__ psum, float* __restrict__ pcnt) {
    int t = blockIdx.x * 256 + threadIdx.x;
    int node = t >> 3;            // grid sized exactly
    int lane = t & 7;
    int beg = start_g[node];
    int cnt = cnt_g[node];
    const float2* base = (const float2*)h2s;
    float2 a = base[(size_t)node * 8 + lane];   // self loop
    int nfull = cnt >> 3;
    int rem = cnt & 7;
    int ev = (nfull > 0) ? esrc[beg + lane]
           : ((lane < rem) ? esrc[beg + lane] : 0);
    for (int c = 0; c < nfull; ++c) {
        int evn = 0;
        if (c + 1 < nfull) evn = esrc[beg + (c + 1) * 8 + lane];
        else if (lane < rem) evn = esrc[beg + nfull * 8 + lane];
        float2 v0 = base[(size_t)__shfl(ev, 0, 8) * 8 + lane];
        float2 v1 = base[(size_t)__shfl(ev, 1, 8) * 8 + lane];
        float2 v2 = base[(size_t)__shfl(ev, 2, 8) * 8 + lane];
        float2 v3 = base[(size_t)__shfl(ev, 3, 8) * 8 + lane];
        float2 v4 = base[(size_t)__shfl(ev, 4, 8) * 8 + lane];
        float2 v5 = base[(size_t)__shfl(ev, 5, 8) * 8 + lane];
        float2 v6 = base[(size_t)__shfl(ev, 6, 8) * 8 + lane];
        float2 v7 = base[(size_t)__shfl(ev, 7, 8) * 8 + lane];
        a.x += ((v0.x + v1.x) + (v2.x + v3.x)) + ((v4.x + v5.x) + (v6.x + v7.x));
        a.y += ((v0.y + v1.y) + (v2.y + v3.y)) + ((v4.y + v5.y) + (v6.y + v7.y));
        ev = evn;
    }
    if (rem) {
#pragma unroll
        for (int j = 0; j < 8; ++j) {
            int sj = __shfl(ev, j, 8);
            bool val = (j < rem);
            float2 v = base[(size_t)(val ? sj : node) * 8 + lane];
            float m = val ? 1.0f : 0.0f;
            a.x += v.x * m; a.y += v.y * m;
        }
    }
    float di = dinv[node];
    float vx = fmaxf(a.x * di + b2[2*lane+0], 0.0f);
    float vy = fmaxf(a.y * di + b2[2*lane+1], 0.0f);
    float c = (lane == 0) ? 1.0f : 0.0f;
    int g = batch[node];
    int wl = threadIdx.x & 63;
    int g0 = __shfl(g, 0);
    bool uni = (__ballot(g == g0) == ~0ull);
    if (uni) {
#pragma unroll
        for (int m = 8; m <= 32; m <<= 1) {
            vx += __shfl_xor(vx, m);
            vy += __shfl_xor(vy, m);
            c  += __shfl_xor(c, m);
        }
        if (wl < 8) {
            unsafeAtomicAdd(&psum[g0 * H2 + 2*wl + 0], vx);
            unsafeAtomicAdd(&psum[g0 * H2 + 2*wl + 1], vy);
        }
        if (wl == 0) unsafeAtomicAdd(&pcnt[g0], c);
    } else {
        unsafeAtomicAdd(&psum[g * H2 + 2*lane + 0], vx);
        unsafeAtomicAdd(&psum[g * H2 + 2*lane + 1], vy);
        if (lane == 0) unsafeAtomicAdd(&pcnt[g], 1.0f);
    }
}

// ---- head: mean, fc, softmax ------------------------------------------------
__global__ void k_head(const float* __restrict__ psum, const float* __restrict__ pcnt,
                       const float* __restrict__ fcw, const float* __restrict__ fcb,
                       float* __restrict__ out) {
    int g = blockIdx.x * 256 + threadIdx.x;
    if (g >= N_GRAPHS) return;
    float inv = 1.0f / fmaxf(pcnt[g], 1.0f);
    float p[H2];
#pragma unroll
    for (int j = 0; j < H2; ++j) p[j] = psum[g * H2 + j] * inv;
    float lg[NCLS];
    float m = -1e30f;
#pragma unroll
    for (int c = 0; c < NCLS; ++c) {
        float s = fcb[c];
#pragma unroll
        for (int j = 0; j < H2; ++j) s += p[j] * fcw[j * NCLS + c];
        lg[c] = s;
        m = fmaxf(m, s);
    }
    float sum = 0.0f;
#pragma unroll
    for (int c = 0; c < NCLS; ++c) { lg[c] = expf(lg[c] - m); sum += lg[c]; }
    float is = 1.0f / sum;
#pragma unroll
    for (int c = 0; c < NCLS; ++c) out[g * NCLS + c] = lg[c] * is;
}

extern "C" void kernel_launch(void* const* d_in, const int* in_sizes, int n_in,
                              void* d_out, int out_size, void* d_ws, size_t ws_size,
                              hipStream_t stream) {
    const float* X   = (const float*)d_in[0];
    const int*   ei  = (const int*)d_in[1];
    const int*   bat = (const int*)d_in[2];
    const float* W1  = (const float*)d_in[3];
    const float* b1  = (const float*)d_in[4];
    const float* W2  = (const float*)d_in[5];
    const float* b2  = (const float*)d_in[6];
    const float* fcw = (const float*)d_in[7];
    const float* fcb = (const float*)d_in[8];
    float* out = (float*)d_out;

    const int* src = ei;
    const int* dst = ei + N_EDGES;

    char* ws = (char*)d_ws;
    int*   bcur  = (int*)ws;    ws += 512 * 4;
    int*   startg= (int*)ws;    ws += (size_t)N_NODES * 4;
    int*   cntg  = (int*)ws;    ws += (size_t)N_NODES * 4;
    float* dinv  = (float*)ws;  ws += (size_t)N_NODES * 4;
    int*   esrc  = (int*)ws;    ws += (size_t)NBUCKET * CAP * 4;   // 16 MB, gapped CSR
    float* h1s   = (float*)ws;  ws += (size_t)N_NODES * H1 * 4;    // 12.8 MB
    float* h2s   = (float*)ws;  ws += (size_t)N_NODES * H2 * 4;    // 6.4 MB
    float* psum  = (float*)ws;  ws += (size_t)N_GRAPHS * H2 * 4;
    float* pcnt  = (float*)ws;
    // ebkt (16 MB) aliases h1s+h2s (19.2 MB): dead before k_gemm1/k_gA write them
    int* ebkt = (int*)h1s;

    int nbN = (N_NODES + 255) / 256;

    k_init  <<<32, 256, 0, stream>>>(bcur, psum, pcnt);
    k_bin   <<<NBINBLK, 512, 0, stream>>>(src, dst, bcur, ebkt);
    k_place3<<<NBUCKET, 256, 0, stream>>>(bcur, ebkt, startg, cntg, dinv, esrc);
    k_gemm1 <<<nbN, 256, 0, stream>>>(X, W1, dinv, h1s);
    k_gA    <<<(N_NODES * 8) / 256, 256, 0, stream>>>(startg, cntg, esrc, h1s, b1, W2, dinv, h2s);
    k_gB    <<<(N_NODES * 8) / 256, 256, 0, stream>>>(startg, cntg, esrc, h2s, b2, dinv, bat, psum, pcnt);
    k_head  <<<(N_GRAPHS + 255) / 256, 256, 0, stream>>>(psum, pcnt, fcw, fcb, out);
}